// Round 6
// baseline (2916.086 us; speedup 1.0000x reference)
//
#include <hip/hip_runtime.h>
#include <hip/hip_bf16.h>
#include <stdint.h>

#define N_IN 250000
#define N_OUT 500000
#define INC 256
#define OUTC 128
#define KVOL 8
#define NTOT (KVOL * N_IN)
#define BN_EPS 1e-5f
#define DCHUNKS 489            // ceil(N_OUT / 1024)
#define OS 500004              // offs8 row stride (N_OUT + 1 sentinel, 16B-aligned)

typedef __bf16 bf16x8_t __attribute__((ext_vector_type(8)));
typedef __bf16 bf16x4_t __attribute__((ext_vector_type(4)));
typedef float f32x4_t __attribute__((ext_vector_type(4)));

__device__ __forceinline__ __bf16 f2bf(float x) {
  union { float f; uint32_t u; } v; v.f = x;
  uint32_t r = v.u + 0x7FFFu + ((v.u >> 16) & 1u);
  union { uint16_t s; __bf16 b; } o; o.s = (uint16_t)(r >> 16);
  return o.b;
}

__device__ __forceinline__ uint32_t pack2bf(float lo, float hi) {
  union { float f; uint32_t u; } a, b; a.f = lo; b.f = hi;
  uint32_t ra = a.u + 0x7FFFu + ((a.u >> 16) & 1u);
  uint32_t rb = b.u + 0x7FFFu + ((b.u >> 16) & 1u);
  return (ra >> 16) | (rb & 0xFFFF0000u);
}

// ======================= conversions =======================

// x[250000][256] f32 -> xb bf16 (8 elems/thread)
__global__ void xconv_kernel(const float* __restrict__ x, uint32_t* __restrict__ xb) {
  int g = blockIdx.x * 256 + threadIdx.x;
  if (g >= N_IN * INC / 8) return;
  const float4* p = (const float4*)x + (size_t)g * 2;
  float4 v0 = p[0], v1 = p[1];
  uint4 o;
  o.x = pack2bf(v0.x, v0.y); o.y = pack2bf(v0.z, v0.w);
  o.z = pack2bf(v1.x, v1.y); o.w = pack2bf(v1.z, v1.w);
  ((uint4*)xb)[g] = o;
}

// W[k][inc][outc] fp32 -> Wt[k][outc][inc] bf16
__global__ void wconv_kernel(const float* __restrict__ W, __bf16* __restrict__ Wt) {
  int f = blockIdx.x * blockDim.x + threadIdx.x;
  if (f >= KVOL * OUTC * INC) return;
  int i = f & (INC - 1);
  int o = (f >> 8) & (OUTC - 1);
  int k = f >> 15;
  Wt[f] = f2bf(W[(k * INC + i) * OUTC + o]);
}

// ======================= per-k counting sort =======================

__global__ void hist8_kernel(const int* __restrict__ oidx, int* __restrict__ cnt8) {
  int i = blockIdx.x * 256 + threadIdx.x;
  int k = blockIdx.y;
  if (i < N_IN) atomicAdd(&cnt8[(size_t)k * N_OUT + oidx[k * N_IN + i]], 1);
}

// per-1024-chunk exclusive scan; in stride N_OUT, out stride OS
__global__ void scan1s_kernel(const int* __restrict__ in, int* __restrict__ out,
                              int* __restrict__ bsum) {
  __shared__ int sd[256];
  int t = threadIdx.x;
  int s = blockIdx.y;
  const int* inp = in + (size_t)s * N_OUT;
  int* outp = out + (size_t)s * OS;
  int base = blockIdx.x * 1024 + t * 4;
  int v0 = 0, v1 = 0, v2 = 0, v3 = 0;
  if (base + 3 < N_OUT) {
    int4 v = *(const int4*)&inp[base];
    v0 = v.x; v1 = v.y; v2 = v.z; v3 = v.w;
  } else {
    if (base     < N_OUT) v0 = inp[base];
    if (base + 1 < N_OUT) v1 = inp[base + 1];
    if (base + 2 < N_OUT) v2 = inp[base + 2];
  }
  int sm = v0 + v1 + v2 + v3;
  sd[t] = sm; __syncthreads();
  for (int o = 1; o < 256; o <<= 1) {
    int a = (t >= o) ? sd[t - o] : 0;
    __syncthreads();
    sd[t] += a;
    __syncthreads();
  }
  int excl = sd[t] - sm;
  if (base     < N_OUT) outp[base]     = excl;
  if (base + 1 < N_OUT) outp[base + 1] = excl + v0;
  if (base + 2 < N_OUT) outp[base + 2] = excl + v0 + v1;
  if (base + 3 < N_OUT) outp[base + 3] = excl + v0 + v1 + v2;
  if (t == 255) bsum[s * DCHUNKS + blockIdx.x] = sd[255];
}

__global__ void scan2s_kernel(const int* __restrict__ bsum, int* __restrict__ bsumx) {
  __shared__ int sd[512];
  int t = threadIdx.x;
  int s = blockIdx.x;
  int v = (t < DCHUNKS) ? bsum[s * DCHUNKS + t] : 0;
  sd[t] = v; __syncthreads();
  for (int o = 1; o < 512; o <<= 1) {
    int a = (t >= o) ? sd[t - o] : 0;
    __syncthreads();
    sd[t] += a;
    __syncthreads();
  }
  if (t < DCHUNKS) bsumx[s * DCHUNKS + t] = sd[t] - v;
}

// finalize offs8 (+sentinel) and copy to fill-cursors cur8
__global__ void scan3s_kernel(int* __restrict__ offs8, int* __restrict__ cur8,
                              const int* __restrict__ bsumx) {
  int g = blockIdx.x * 256 + threadIdx.x;
  int s = blockIdx.y;
  if (g < N_OUT) {
    int v = offs8[(size_t)s * OS + g] + bsumx[s * DCHUNKS + (g >> 10)];
    offs8[(size_t)s * OS + g] = v;
    cur8[(size_t)s * N_OUT + g] = v;
  }
  if (g == 0) offs8[(size_t)s * OS + N_OUT] = N_IN;
}

// build per-k d-sorted stream of {src_i, d}
__global__ void fill_kernel(const int* __restrict__ oidx, int* __restrict__ cur8,
                            int2* __restrict__ ssd) {
  int i = blockIdx.x * 256 + threadIdx.x;
  int k = blockIdx.y;
  if (i < N_IN) {
    int d = oidx[k * N_IN + i];
    int j = atomicAdd(&cur8[(size_t)k * N_OUT + d], 1);
    ssd[(size_t)k * N_IN + j] = make_int2(i, d);
  }
}

// ============== fused gather-GEMM + LDS accumulate + BN stats ==============

#define DR 128   // output rows per block

// 512 thr = 8 waves. Block owns output rows [dbase, dbase+DR). For each k:
// stage W[k] in LDS, then consume this block's k-contributions in batches of
// 32 gathered x rows; MFMA (D[voxel][chan]) and ds-atomic-add into the f32
// LDS accumulator. Epilogue: fused per-channel sum/sumsq + f32 row writeout.
__global__ __launch_bounds__(512, 1) void fused_gemm_acc_kernel(
    const char* __restrict__ xbb, const __bf16* __restrict__ Wt,
    const int2* __restrict__ ssd, const int* __restrict__ offs8,
    float* __restrict__ outF, float* __restrict__ stats) {
  __shared__ float acc[DR][136];        // 69,632 B (stride 136: v-groups 8 banks apart)
  __shared__ __bf16 Wk[OUTC * 256];     // 65,536 B, XOR-swizzled rows
  __shared__ __bf16 xstage[32 * 256];   // 16,384 B, XOR-swizzled rows
  __shared__ float red[8][128];         //  4,096 B
  __shared__ int s_d[32];

  const int t = threadIdx.x;
  const int dbase = blockIdx.x * DR;
  const int dend = min(dbase + DR, N_OUT);
  const int nvalid = dend - dbase;

  for (int i = t; i < DR * 136; i += 512) ((float*)acc)[i] = 0.f;
  __syncthreads();

  const int w = t >> 6, l = t & 63, lr = l & 15, lg = l >> 4;
  const int swz = (lr & 7) << 3;        // row-XOR swizzle for frag reads

  for (int k = 0; k < KVOL; ++k) {
    // ---- stage W[k] (row-major [128][256] bf16) into swizzled LDS ----
    {
      const uint4* src = (const uint4*)(Wt + (size_t)k * OUTC * INC);
      int row = t >> 2, qt = t & 3;     // 4 threads/row, 8 pieces each
      #pragma unroll
      for (int j = 0; j < 8; ++j) {
        int piece = qt * 8 + j;         // 16B piece (8 bf16)
        int es = (piece * 8) ^ ((row & 7) << 3);
        *(uint4*)&Wk[row * 256 + es] = src[row * 32 + piece];
      }
    }
    __syncthreads();

    // hoist B-fragments for this k (wave w -> chans 16w..16w+15)
    bf16x8_t bfr[8];
    #pragma unroll
    for (int s = 0; s < 8; ++s)
      bfr[s] = *(const bf16x8_t*)&Wk[((w << 4) + lr) * 256 + ((s * 32 + lg * 8) ^ swz)];

    const int o0 = offs8[(size_t)k * OS + dbase];
    const int o1 = offs8[(size_t)k * OS + dend];
    const int cnt = o1 - o0;

    for (int b0 = 0; b0 < cnt; b0 += 32) {
      // ---- gather 32 x rows (512 B each) into swizzled LDS ----
      {
        int row = t >> 4, pc2 = (t & 15) * 2;
        int j = b0 + row;
        int2 sd = (j < cnt) ? ssd[(size_t)k * N_IN + o0 + j] : make_int2(-1, dbase);
        if ((t & 15) == 0) s_d[row] = (sd.x < 0) ? 0 : (sd.y - dbase);
        #pragma unroll
        for (int q = 0; q < 2; ++q) {
          int piece = pc2 + q;
          uint4 v = make_uint4(0u, 0u, 0u, 0u);
          if (sd.x >= 0) v = *(const uint4*)(xbb + (size_t)sd.x * 512 + piece * 16);
          int es = (piece * 8) ^ ((row & 7) << 3);
          *(uint4*)&xstage[row * 256 + es] = v;
        }
      }
      __syncthreads();

      // ---- compute 32 voxels x 128 chans; wave w covers chans 16w.. ----
      #pragma unroll
      for (int m = 0; m < 2; ++m) {
        f32x4_t D = {0.f, 0.f, 0.f, 0.f};
        #pragma unroll
        for (int s = 0; s < 8; ++s) {
          bf16x8_t a = *(const bf16x8_t*)
              &xstage[(m * 16 + lr) * 256 + ((s * 32 + lg * 8) ^ swz)];
          D = __builtin_amdgcn_mfma_f32_16x16x32_bf16(a, bfr[s], D, 0, 0, 0);
        }
        int c = (w << 4) + lr;          // D col = chan
        #pragma unroll
        for (int reg = 0; reg < 4; ++reg)
          atomicAdd(&acc[s_d[m * 16 + lg * 4 + reg]][c], D[reg]);
      }
      __syncthreads();
    }
  }
  __syncthreads();

  // ---- fused BN partial stats from the f32 accumulator ----
  {
    int c = t & 127, grp = t >> 7;
    float sm = 0.f, sq = 0.f;
    for (int r = grp; r < DR; r += 4) {
      float v = acc[r][c];
      sm += v; sq += v * v;
    }
    red[grp][c] = sm;
    red[4 + grp][c] = sq;
  }
  __syncthreads();
  if (t < 128) {
    atomicAdd(&stats[t], red[0][t] + red[1][t] + red[2][t] + red[3][t]);
  } else if (t < 256) {
    int c = t - 128;
    atomicAdd(&stats[128 + c], red[4][c] + red[5][c] + red[6][c] + red[7][c]);
  }

  // ---- write f32 rows to d_out ----
  {
    int row = t >> 2, qt = t & 3;
    if (row < nvalid) {
      float* dst = outF + (size_t)(dbase + row) * OUTC + qt * 32;
      const float* srcr = &acc[row][qt * 32];
      #pragma unroll
      for (int j = 0; j < 8; ++j)
        *(float4*)&dst[j * 4] = *(const float4*)&srcr[j * 4];
    }
  }
}

// ======================= BN normalize (in-place f32) =======================

__global__ void norm_f32_kernel(float* __restrict__ out, const float* __restrict__ stats,
                                const float* __restrict__ gamma, const float* __restrict__ beta) {
  const int t = threadIdx.x;
  const int c4 = t & 31;
  const int ro = t >> 5;
  const float inv_n = 1.0f / (float)N_OUT;
  float sc[4], sh[4];
  #pragma unroll
  for (int j = 0; j < 4; ++j) {
    int c = c4 * 4 + j;
    float mean = stats[c] * inv_n;
    float var  = stats[128 + c] * inv_n - mean * mean;
    float s = gamma[c] * rsqrtf(var + BN_EPS);
    sc[j] = s;
    sh[j] = beta[c] - mean * s;
  }
  for (int r = blockIdx.x * 8 + ro; r < N_OUT; r += gridDim.x * 8) {
    f32x4_t v = ((const f32x4_t*)out)[(size_t)r * 32 + c4];
    #pragma unroll
    for (int j = 0; j < 4; ++j) v[j] = v[j] * sc[j] + sh[j];
    ((f32x4_t*)out)[(size_t)r * 32 + c4] = v;
  }
}

// ======================= fallback (round-2 proven atomic path) =======================

#define LDS_STRIDE 264

__global__ __launch_bounds__(512, 1) void gemm_scatter_f32_kernel(
    const float* __restrict__ x, const __bf16* __restrict__ Wt,
    const int* __restrict__ out_idx, float* __restrict__ acc) {
  __shared__ __bf16 xs[64 * LDS_STRIDE];
  const int t = threadIdx.x;
  const int row0 = blockIdx.x * 64;
  #pragma unroll
  for (int i = 0; i < 8; ++i) {
    int f = t + i * 512;
    int r = f >> 6;
    int c4 = f & 63;
    int grow = row0 + r;
    float4 v = make_float4(0.f, 0.f, 0.f, 0.f);
    if (grow < N_IN) v = ((const float4*)x)[(size_t)grow * 64 + c4];
    bf16x4_t bv;
    bv[0] = f2bf(v.x); bv[1] = f2bf(v.y); bv[2] = f2bf(v.z); bv[3] = f2bf(v.w);
    *(bf16x4_t*)&xs[r * LDS_STRIDE + c4 * 4] = bv;
  }
  __syncthreads();
  const int w = t >> 6, l = t & 63, lr = l & 15, lg = l >> 4;
  f32x4_t accr[4][8];
  #pragma unroll
  for (int m = 0; m < 4; ++m)
    #pragma unroll
    for (int n = 0; n < 8; ++n)
      accr[m][n] = (f32x4_t){0.f, 0.f, 0.f, 0.f};
  const __bf16* Wkp = Wt + (size_t)w * OUTC * INC;
  #pragma unroll
  for (int s = 0; s < 8; ++s) {
    bf16x8_t a[4], b[8];
    #pragma unroll
    for (int m = 0; m < 4; ++m)
      a[m] = *(const bf16x8_t*)&xs[(m * 16 + lr) * LDS_STRIDE + s * 32 + lg * 8];
    #pragma unroll
    for (int n = 0; n < 8; ++n)
      b[n] = *(const bf16x8_t*)&Wkp[(n * 16 + lr) * INC + s * 32 + lg * 8];
    #pragma unroll
    for (int m = 0; m < 4; ++m)
      #pragma unroll
      for (int n = 0; n < 8; ++n)
        accr[m][n] = __builtin_amdgcn_mfma_f32_16x16x32_bf16(a[m], b[n], accr[m][n], 0, 0, 0);
  }
  const int* oidx = out_idx + (size_t)w * N_IN;
  #pragma unroll
  for (int m = 0; m < 4; ++m) {
    int rbase = m * 16 + lg * 4;
    #pragma unroll
    for (int reg = 0; reg < 4; ++reg) {
      int grow = row0 + rbase + reg;
      if (grow < N_IN) {
        int dst = oidx[grow];
        float* ap = acc + (size_t)dst * OUTC;
        #pragma unroll
        for (int n = 0; n < 8; ++n)
          atomicAdd(&ap[n * 16 + lr], accr[m][n][reg]);
      }
    }
  }
}

__global__ void stats_f32_kernel(const float* __restrict__ acc, float* __restrict__ stats) {
  const int t = threadIdx.x;
  const int c4 = t & 31;
  const int ro = t >> 5;
  f32x4_t s = {0.f, 0.f, 0.f, 0.f}, q = {0.f, 0.f, 0.f, 0.f};
  for (int r = blockIdx.x * 8 + ro; r < N_OUT; r += gridDim.x * 8) {
    f32x4_t v = ((const f32x4_t*)acc)[(size_t)r * 32 + c4];
    s += v; q += v * v;
  }
  __shared__ float redl[256][8];
  #pragma unroll
  for (int j = 0; j < 4; ++j) { redl[t][j] = s[j]; redl[t][4 + j] = q[j]; }
  __syncthreads();
  if (t < 32) {
    float S[4] = {0.f, 0.f, 0.f, 0.f}, Q[4] = {0.f, 0.f, 0.f, 0.f};
    for (int r2 = 0; r2 < 8; ++r2)
      #pragma unroll
      for (int j = 0; j < 4; ++j) {
        S[j] += redl[r2 * 32 + t][j];
        Q[j] += redl[r2 * 32 + t][4 + j];
      }
    #pragma unroll
    for (int j = 0; j < 4; ++j) {
      atomicAdd(&stats[t * 4 + j], S[j]);
      atomicAdd(&stats[128 + t * 4 + j], Q[j]);
    }
  }
}

// ======================= launch =======================

extern "C" void kernel_launch(void* const* d_in, const int* in_sizes, int n_in,
                              void* d_out, int out_size, void* d_ws, size_t ws_size,
                              hipStream_t stream) {
  const float* x     = (const float*)d_in[0];
  const float* W     = (const float*)d_in[1];
  const float* gamma = (const float*)d_in[2];
  const float* beta  = (const float*)d_in[3];
  const int*   oidx  = (const int*)d_in[4];

  // ws layout
  const size_t XB_OFF    = 0;             // 128,000,000
  const size_t CNT8_OFF  = 128000000;     //  16,000,000
  const size_t CUR8_OFF  = 144000000;     //  16,000,000
  const size_t OFFS8_OFF = 160000000;     //  16,000,128 (8 x OS ints)
  const size_t SSD_OFF   = 176000128;     //  16,000,000 (int2 x 2M)
  const size_t WT_OFF    = 192000128;     //     524,288
  const size_t BSUM_OFF  = 192524416;     //      16,000
  const size_t BSUMX_OFF = 192540416;     //      16,000
  const size_t STATS_OFF = 192556416;     //       1,024
  const size_t NEED      = 192557440;

  if (ws_size >= NEED) {
    char* ws = (char*)d_ws;
    char* xbb    = ws + XB_OFF;
    int* cnt8    = (int*)(ws + CNT8_OFF);
    int* cur8    = (int*)(ws + CUR8_OFF);
    int* offs8   = (int*)(ws + OFFS8_OFF);
    int2* ssd    = (int2*)(ws + SSD_OFF);
    __bf16* Wt   = (__bf16*)(ws + WT_OFF);
    int* bsum8   = (int*)(ws + BSUM_OFF);
    int* bsumx8  = (int*)(ws + BSUMX_OFF);
    float* stats = (float*)(ws + STATS_OFF);

    hipMemsetAsync(cnt8, 0, (size_t)KVOL * N_OUT * sizeof(int), stream);
    hipMemsetAsync(stats, 0, 256 * sizeof(float), stream);

    xconv_kernel<<<(N_IN * INC / 8 + 255) / 256, 256, 0, stream>>>(x, (uint32_t*)xbb);
    wconv_kernel<<<(KVOL * OUTC * INC + 255) / 256, 256, 0, stream>>>(W, Wt);
    hist8_kernel<<<dim3((N_IN + 255) / 256, KVOL), 256, 0, stream>>>(oidx, cnt8);
    scan1s_kernel<<<dim3(DCHUNKS, KVOL), 256, 0, stream>>>(cnt8, offs8, bsum8);
    scan2s_kernel<<<KVOL, 512, 0, stream>>>(bsum8, bsumx8);
    scan3s_kernel<<<dim3((N_OUT + 255) / 256, KVOL), 256, 0, stream>>>(offs8, cur8, bsumx8);
    fill_kernel<<<dim3((N_IN + 255) / 256, KVOL), 256, 0, stream>>>(oidx, cur8, ssd);
    fused_gemm_acc_kernel<<<(N_OUT + DR - 1) / DR, 512, 0, stream>>>(
        xbb, Wt, ssd, offs8, (float*)d_out, stats);
    norm_f32_kernel<<<2048, 256, 0, stream>>>((float*)d_out, stats, gamma, beta);
  } else {
    // fallback: proven round-2 atomic pipeline (~526 KB ws)
    __bf16* Wt   = (__bf16*)d_ws;
    float* stats = (float*)((char*)d_ws + (size_t)KVOL * OUTC * INC * 2);
    float* out = (float*)d_out;

    hipMemsetAsync(d_out, 0, (size_t)N_OUT * OUTC * sizeof(float), stream);
    hipMemsetAsync(stats, 0, 256 * sizeof(float), stream);

    wconv_kernel<<<(KVOL * OUTC * INC + 255) / 256, 256, 0, stream>>>(W, Wt);
    gemm_scatter_f32_kernel<<<(N_IN + 63) / 64, 512, 0, stream>>>(x, Wt, oidx, out);
    stats_f32_kernel<<<1024, 256, 0, stream>>>(out, stats);
    norm_f32_kernel<<<2048, 256, 0, stream>>>(out, stats, gamma, beta);
  }
}

// Round 7
// 2591.543 us; speedup vs baseline: 1.1252x; 1.1252x over previous
//
#include <hip/hip_runtime.h>
#include <hip/hip_bf16.h>
#include <stdint.h>

#define N_IN 250000
#define N_OUT 500000
#define INC 256
#define OUTC 128
#define KVOL 8
#define NTOT (KVOL * N_IN)
#define BN_EPS 1e-5f
#define DCHUNKS 489            // ceil(N_OUT / 1024)
#define OS 500004              // offs8 row stride (N_OUT + 1 sentinel, 16B-aligned)
#define NPASS 8
#define DPASS 62500            // d-rows per pass
#define PARTCAP 280000         // partials slots (pass max ~250K + 64 sigma)

typedef __bf16 bf16x8_t __attribute__((ext_vector_type(8)));
typedef __bf16 bf16x4_t __attribute__((ext_vector_type(4)));
typedef float f32x4_t __attribute__((ext_vector_type(4)));

__device__ __forceinline__ __bf16 f2bf(float x) {
  union { float f; uint32_t u; } v; v.f = x;
  uint32_t r = v.u + 0x7FFFu + ((v.u >> 16) & 1u);
  union { uint16_t s; __bf16 b; } o; o.s = (uint16_t)(r >> 16);
  return o.b;
}

__device__ __forceinline__ uint32_t pack2bf(float lo, float hi) {
  union { float f; uint32_t u; } a, b; a.f = lo; b.f = hi;
  uint32_t ra = a.u + 0x7FFFu + ((a.u >> 16) & 1u);
  uint32_t rb = b.u + 0x7FFFu + ((b.u >> 16) & 1u);
  return (ra >> 16) | (rb & 0xFFFF0000u);
}

__device__ __forceinline__ float bflo(uint32_t w) {
  union { uint32_t u; float f; } v; v.u = w << 16; return v.f;
}
__device__ __forceinline__ float bfhi(uint32_t w) {
  union { uint32_t u; float f; } v; v.u = w & 0xFFFF0000u; return v.f;
}

// ======================= conversions =======================

__global__ void xconv_kernel(const float* __restrict__ x, uint32_t* __restrict__ xb) {
  int g = blockIdx.x * 256 + threadIdx.x;
  if (g >= N_IN * INC / 8) return;
  const float4* p = (const float4*)x + (size_t)g * 2;
  float4 v0 = p[0], v1 = p[1];
  uint4 o;
  o.x = pack2bf(v0.x, v0.y); o.y = pack2bf(v0.z, v0.w);
  o.z = pack2bf(v1.x, v1.y); o.w = pack2bf(v1.z, v1.w);
  ((uint4*)xb)[g] = o;
}

__global__ void wconv_kernel(const float* __restrict__ W, __bf16* __restrict__ Wt) {
  int f = blockIdx.x * blockDim.x + threadIdx.x;
  if (f >= KVOL * OUTC * INC) return;
  int i = f & (INC - 1);
  int o = (f >> 8) & (OUTC - 1);
  int k = f >> 15;
  Wt[f] = f2bf(W[(k * INC + i) * OUTC + o]);
}

// ======================= counting sort (per-k + global) =======================

__global__ void hist8_kernel(const int* __restrict__ oidx, int* __restrict__ cnt8,
                             int* __restrict__ gcnt) {
  int i = blockIdx.x * 256 + threadIdx.x;
  int k = blockIdx.y;
  if (i < N_IN) {
    int d = oidx[k * N_IN + i];
    atomicAdd(&cnt8[(size_t)k * N_OUT + d], 1);
    atomicAdd(&gcnt[d], 1);
  }
}

// per-1024-chunk exclusive scan; in stride N_OUT, out stride OS
__global__ void scan1s_kernel(const int* __restrict__ in, int* __restrict__ out,
                              int* __restrict__ bsum) {
  __shared__ int sd[256];
  int t = threadIdx.x;
  int s = blockIdx.y;
  const int* inp = in + (size_t)s * N_OUT;
  int* outp = out + (size_t)s * OS;
  int base = blockIdx.x * 1024 + t * 4;
  int v0 = 0, v1 = 0, v2 = 0, v3 = 0;
  if (base + 3 < N_OUT) {
    int4 v = *(const int4*)&inp[base];
    v0 = v.x; v1 = v.y; v2 = v.z; v3 = v.w;
  } else {
    if (base     < N_OUT) v0 = inp[base];
    if (base + 1 < N_OUT) v1 = inp[base + 1];
    if (base + 2 < N_OUT) v2 = inp[base + 2];
  }
  int sm = v0 + v1 + v2 + v3;
  sd[t] = sm; __syncthreads();
  for (int o = 1; o < 256; o <<= 1) {
    int a = (t >= o) ? sd[t - o] : 0;
    __syncthreads();
    sd[t] += a;
    __syncthreads();
  }
  int excl = sd[t] - sm;
  if (base     < N_OUT) outp[base]     = excl;
  if (base + 1 < N_OUT) outp[base + 1] = excl + v0;
  if (base + 2 < N_OUT) outp[base + 2] = excl + v0 + v1;
  if (base + 3 < N_OUT) outp[base + 3] = excl + v0 + v1 + v2;
  if (t == 255) bsum[s * DCHUNKS + blockIdx.x] = sd[255];
}

__global__ void scan2s_kernel(const int* __restrict__ bsum, int* __restrict__ bsumx) {
  __shared__ int sd[512];
  int t = threadIdx.x;
  int s = blockIdx.x;
  int v = (t < DCHUNKS) ? bsum[s * DCHUNKS + t] : 0;
  sd[t] = v; __syncthreads();
  for (int o = 1; o < 512; o <<= 1) {
    int a = (t >= o) ? sd[t - o] : 0;
    __syncthreads();
    sd[t] += a;
    __syncthreads();
  }
  if (t < DCHUNKS) bsumx[s * DCHUNKS + t] = sd[t] - v;
}

// finalize per-k offs8 (+sentinel) and fill-cursors cur8
__global__ void scan3s_kernel(int* __restrict__ offs8, int* __restrict__ cur8,
                              const int* __restrict__ bsumx) {
  int g = blockIdx.x * 256 + threadIdx.x;
  int s = blockIdx.y;
  if (g < N_OUT) {
    int v = offs8[(size_t)s * OS + g] + bsumx[s * DCHUNKS + (g >> 10)];
    offs8[(size_t)s * OS + g] = v;
    cur8[(size_t)s * N_OUT + g] = v;
  }
  if (g == 0) offs8[(size_t)s * OS + N_OUT] = N_IN;
}

// finalize global goffs (+sentinel) and gcur
__global__ void scan3g_kernel(int* __restrict__ goffs, int* __restrict__ gcur,
                              const int* __restrict__ bsumx) {
  int g = blockIdx.x * 256 + threadIdx.x;
  if (g < N_OUT) {
    int v = goffs[g] + bsumx[g >> 10];
    goffs[g] = v;
    gcur[g] = v;
  }
  if (g == 0) goffs[N_OUT] = NTOT;
}

// build per-k d-sorted stream: source row + global d-sorted slot
__global__ void fill_kernel(const int* __restrict__ oidx, int* __restrict__ cur8,
                            int* __restrict__ gcur, int* __restrict__ ssrc,
                            int* __restrict__ sgslot) {
  int i = blockIdx.x * 256 + threadIdx.x;
  int k = blockIdx.y;
  if (i < N_IN) {
    int d = oidx[k * N_IN + i];
    int j = atomicAdd(&cur8[(size_t)k * N_OUT + d], 1);
    int g = atomicAdd(&gcur[d], 1);
    ssrc[k * N_IN + j] = i;
    sgslot[k * N_IN + j] = g;
  }
}

// ======================= pass-tiled gather-GEMM -> partials =======================

#define GTM 64
#define LDS_STRIDE 264

// grid (512, 8). Block = (k, grid-stride chunks of 64 d-sorted slots within
// [offs8[k][dlo], offs8[k][dhi])). Gathers x_bf16 rows (L3-resident within a
// pass), MFMA D[chan][voxel], writes 256B partial rows at (sgslot - gbase)
// into the pass-local 72MB partials buffer (MALL-resident).
__global__ __launch_bounds__(512, 1) void gemm_gather_store_kernel(
    const char* __restrict__ xbb, const __bf16* __restrict__ Wt,
    const int* __restrict__ ssrc, const int* __restrict__ sgslot,
    const int* __restrict__ offs8, const int* __restrict__ goffs,
    char* __restrict__ partials, int dlo, int dhi) {
  __shared__ __bf16 xs[GTM * LDS_STRIDE];  // 33792 B
  __shared__ uint2 stg[GTM][34];           // 17408 B
  __shared__ int s_src[GTM], s_gsl[GTM];
  const int t = threadIdx.x;
  const int k = blockIdx.y;
  const int j0 = offs8[(size_t)k * OS + dlo];
  const int j1 = offs8[(size_t)k * OS + dhi];
  const int gbase = goffs[dlo];

  const int w = t >> 6, l = t & 63, lr = l & 15, lg = l >> 4;
  const int m  = w >> 1;   // voxel quarter
  const int nh = w & 1;    // channel half
  const __bf16* Wk = Wt + (size_t)k * OUTC * INC;

  for (int c0 = j0 + blockIdx.x * GTM; c0 < j1; c0 += gridDim.x * GTM) {
    if (t < GTM) {
      int sl = c0 + t;
      s_src[t] = (sl < j1) ? ssrc[k * N_IN + sl] : -1;
      s_gsl[t] = (sl < j1) ? sgslot[k * N_IN + sl] : -1;
    }
    __syncthreads();

    // gather: 32-thread group loads one row's 512B; 16 rows/pass
    #pragma unroll
    for (int ii = 0; ii < 4; ++ii) {
      int r = ii * 16 + (t >> 5);
      int off = t & 31;
      int src = s_src[r];
      uint4 v = {0u, 0u, 0u, 0u};
      if (src >= 0) v = *(const uint4*)(xbb + (size_t)src * 512 + off * 16);
      *(uint4*)&xs[r * LDS_STRIDE + off * 8] = v;
    }
    __syncthreads();

    f32x4_t accT[4];
    #pragma unroll
    for (int n = 0; n < 4; ++n) accT[n] = (f32x4_t){0.f, 0.f, 0.f, 0.f};

    #pragma unroll
    for (int s = 0; s < 8; ++s) {
      bf16x8_t a = *(const bf16x8_t*)&xs[(m * 16 + lr) * LDS_STRIDE + s * 32 + lg * 8];
      #pragma unroll
      for (int n = 0; n < 4; ++n) {
        bf16x8_t b = *(const bf16x8_t*)&Wk[((nh * 4 + n) * 16 + lr) * INC + s * 32 + lg * 8];
        accT[n] = __builtin_amdgcn_mfma_f32_16x16x32_bf16(b, a, accT[n], 0, 0, 0);
      }
    }

    #pragma unroll
    for (int n = 0; n < 4; ++n) {
      uint2 pk;
      pk.x = pack2bf(accT[n][0], accT[n][1]);
      pk.y = pack2bf(accT[n][2], accT[n][3]);
      stg[m * 16 + lr][(nh * 4 + n) * 4 + lg] = pk;
    }
    __syncthreads();

    {
      int r = t >> 3, p = t & 7;
      int gs = s_gsl[r];
      if (gs >= 0) {
        const uint4* rp = (const uint4*)&stg[r][0];
        char* dst = partials + (size_t)(gs - gbase) * 256 + p * 32;
        *(uint4*)(dst)      = rp[p * 2];
        *(uint4*)(dst + 16) = rp[p * 2 + 1];
      }
    }
    __syncthreads();   // protect s_src/s_gsl/stg before next chunk
  }
}

// ============== pass-tiled segmented reduce + fused BN stats ==============

__global__ __launch_bounds__(256) void reduce_stats_kernel(
    const char* __restrict__ partials, const int* __restrict__ goffs,
    char* __restrict__ accb, float* __restrict__ stats, int dlo, int dhi) {
  const int t = threadIdx.x;
  const int lane16 = t & 15;
  const int grp = t >> 4;
  const int gbase = goffs[dlo];
  float s[8], q[8];
  #pragma unroll
  for (int i = 0; i < 8; ++i) { s[i] = 0.f; q[i] = 0.f; }

  for (int d = dlo + blockIdx.x * 16 + grp; d < dhi; d += gridDim.x * 16) {
    int j0 = goffs[d] - gbase, j1 = goffs[d + 1] - gbase;
    float a[8];
    #pragma unroll
    for (int i = 0; i < 8; ++i) a[i] = 0.f;
    for (int j = j0; j < j1; ++j) {
      uint4 v = *(const uint4*)(partials + (size_t)j * 256 + lane16 * 16);
      a[0] += bflo(v.x); a[1] += bfhi(v.x);
      a[2] += bflo(v.y); a[3] += bfhi(v.y);
      a[4] += bflo(v.z); a[5] += bfhi(v.z);
      a[6] += bflo(v.w); a[7] += bfhi(v.w);
    }
    uint4 o;
    o.x = pack2bf(a[0], a[1]); o.y = pack2bf(a[2], a[3]);
    o.z = pack2bf(a[4], a[5]); o.w = pack2bf(a[6], a[7]);
    *(uint4*)(accb + (size_t)d * 512 + lane16 * 16) = o;
    uint32_t wd[4] = {o.x, o.y, o.z, o.w};
    #pragma unroll
    for (int u = 0; u < 4; ++u) {
      float f0 = bflo(wd[u]), f1 = bfhi(wd[u]);
      s[2 * u] += f0;     q[2 * u] += f0 * f0;
      s[2 * u + 1] += f1; q[2 * u + 1] += f1 * f1;
    }
  }

  __shared__ float reds[16][16][8];
  __shared__ float redq[16][16][8];
  #pragma unroll
  for (int i = 0; i < 8; ++i) { reds[grp][lane16][i] = s[i]; redq[grp][lane16][i] = q[i]; }
  __syncthreads();
  if (t < 128) {
    float acc = 0.f;
    #pragma unroll
    for (int g2 = 0; g2 < 16; ++g2) acc += reds[g2][t >> 3][t & 7];
    atomicAdd(&stats[t], acc);
  } else {
    int c = t - 128;
    float acc = 0.f;
    #pragma unroll
    for (int g2 = 0; g2 < 16; ++g2) acc += redq[g2][c >> 3][c & 7];
    atomicAdd(&stats[128 + c], acc);
  }
}

// Read bf16 accum from row slot, write normalized fp32 over the full slot.
__global__ void norm_kernel(char* __restrict__ outb, const float* __restrict__ stats,
                            const float* __restrict__ gamma, const float* __restrict__ beta) {
  const int t = threadIdx.x;
  const int j = t & 15;
  const int ro = t >> 4;
  const float inv_n = 1.0f / (float)N_OUT;
  float sc[8], sh[8];
  #pragma unroll
  for (int i = 0; i < 8; ++i) {
    int c = j * 8 + i;
    float mean = stats[c] * inv_n;
    float var  = stats[128 + c] * inv_n - mean * mean;
    float s = gamma[c] * rsqrtf(var + BN_EPS);
    sc[i] = s;
    sh[i] = beta[c] - mean * s;
  }
  for (int r = blockIdx.x * 16 + ro; r < N_OUT; r += gridDim.x * 16) {
    uint4 v = *(const uint4*)(outb + (size_t)r * 512 + j * 16);
    uint32_t wds[4] = {v.x, v.y, v.z, v.w};
    f32x4_t o0, o1;
    #pragma unroll
    for (int u = 0; u < 4; ++u) {
      float f0 = bflo(wds[u]) * sc[2 * u] + sh[2 * u];
      float f1 = bfhi(wds[u]) * sc[2 * u + 1] + sh[2 * u + 1];
      if (u < 2) { o0[2 * u] = f0; o0[2 * u + 1] = f1; }
      else       { o1[2 * (u - 2)] = f0; o1[2 * (u - 2) + 1] = f1; }
    }
    *(f32x4_t*)(outb + (size_t)r * 512 + j * 32) = o0;
    *(f32x4_t*)(outb + (size_t)r * 512 + j * 32 + 16) = o1;
  }
}

// ======================= fallback (round-2 proven atomic path) =======================

__global__ __launch_bounds__(512, 1) void gemm_scatter_f32_kernel(
    const float* __restrict__ x, const __bf16* __restrict__ Wt,
    const int* __restrict__ out_idx, float* __restrict__ acc) {
  __shared__ __bf16 xs[GTM * LDS_STRIDE];
  const int t = threadIdx.x;
  const int row0 = blockIdx.x * GTM;
  #pragma unroll
  for (int i = 0; i < 8; ++i) {
    int f = t + i * 512;
    int r = f >> 6;
    int c4 = f & 63;
    int grow = row0 + r;
    float4 v = make_float4(0.f, 0.f, 0.f, 0.f);
    if (grow < N_IN) v = ((const float4*)x)[(size_t)grow * 64 + c4];
    bf16x4_t bv;
    bv[0] = f2bf(v.x); bv[1] = f2bf(v.y); bv[2] = f2bf(v.z); bv[3] = f2bf(v.w);
    *(bf16x4_t*)&xs[r * LDS_STRIDE + c4 * 4] = bv;
  }
  __syncthreads();
  const int w = t >> 6, l = t & 63, lr = l & 15, lg = l >> 4;
  f32x4_t accr[4][8];
  #pragma unroll
  for (int m = 0; m < 4; ++m)
    #pragma unroll
    for (int n = 0; n < 8; ++n)
      accr[m][n] = (f32x4_t){0.f, 0.f, 0.f, 0.f};
  const __bf16* Wkp = Wt + (size_t)w * OUTC * INC;
  #pragma unroll
  for (int s = 0; s < 8; ++s) {
    bf16x8_t a[4], b[8];
    #pragma unroll
    for (int m = 0; m < 4; ++m)
      a[m] = *(const bf16x8_t*)&xs[(m * 16 + lr) * LDS_STRIDE + s * 32 + lg * 8];
    #pragma unroll
    for (int n = 0; n < 8; ++n)
      b[n] = *(const bf16x8_t*)&Wkp[(n * 16 + lr) * INC + s * 32 + lg * 8];
    #pragma unroll
    for (int m = 0; m < 4; ++m)
      #pragma unroll
      for (int n = 0; n < 8; ++n)
        accr[m][n] = __builtin_amdgcn_mfma_f32_16x16x32_bf16(a[m], b[n], accr[m][n], 0, 0, 0);
  }
  const int* oidx = out_idx + (size_t)w * N_IN;
  #pragma unroll
  for (int m = 0; m < 4; ++m) {
    int rbase = m * 16 + lg * 4;
    #pragma unroll
    for (int reg = 0; reg < 4; ++reg) {
      int grow = row0 + rbase + reg;
      if (grow < N_IN) {
        int dst = oidx[grow];
        float* ap = acc + (size_t)dst * OUTC;
        #pragma unroll
        for (int n = 0; n < 8; ++n)
          atomicAdd(&ap[n * 16 + lr], accr[m][n][reg]);
      }
    }
  }
}

__global__ void stats_f32_kernel(const float* __restrict__ acc, float* __restrict__ stats) {
  const int t = threadIdx.x;
  const int c4 = t & 31;
  const int ro = t >> 5;
  f32x4_t s = {0.f, 0.f, 0.f, 0.f}, q = {0.f, 0.f, 0.f, 0.f};
  for (int r = blockIdx.x * 8 + ro; r < N_OUT; r += gridDim.x * 8) {
    f32x4_t v = ((const f32x4_t*)acc)[(size_t)r * 32 + c4];
    s += v; q += v * v;
  }
  __shared__ float redl[256][8];
  #pragma unroll
  for (int j = 0; j < 4; ++j) { redl[t][j] = s[j]; redl[t][4 + j] = q[j]; }
  __syncthreads();
  if (t < 32) {
    float S[4] = {0.f, 0.f, 0.f, 0.f}, Q[4] = {0.f, 0.f, 0.f, 0.f};
    for (int r2 = 0; r2 < 8; ++r2)
      #pragma unroll
      for (int j = 0; j < 4; ++j) {
        S[j] += redl[r2 * 32 + t][j];
        Q[j] += redl[r2 * 32 + t][4 + j];
      }
    #pragma unroll
    for (int j = 0; j < 4; ++j) {
      atomicAdd(&stats[t * 4 + j], S[j]);
      atomicAdd(&stats[128 + t * 4 + j], Q[j]);
    }
  }
}

__global__ void norm_f32_kernel(float* __restrict__ out, const float* __restrict__ stats,
                                const float* __restrict__ gamma, const float* __restrict__ beta) {
  const int t = threadIdx.x;
  const int c4 = t & 31;
  const int ro = t >> 5;
  const float inv_n = 1.0f / (float)N_OUT;
  float sc[4], sh[4];
  #pragma unroll
  for (int j = 0; j < 4; ++j) {
    int c = c4 * 4 + j;
    float mean = stats[c] * inv_n;
    float var  = stats[128 + c] * inv_n - mean * mean;
    float s = gamma[c] * rsqrtf(var + BN_EPS);
    sc[j] = s;
    sh[j] = beta[c] - mean * s;
  }
  for (int r = blockIdx.x * 8 + ro; r < N_OUT; r += gridDim.x * 8) {
    f32x4_t v = ((const f32x4_t*)out)[(size_t)r * 32 + c4];
    #pragma unroll
    for (int j = 0; j < 4; ++j) v[j] = v[j] * sc[j] + sh[j];
    ((f32x4_t*)out)[(size_t)r * 32 + c4] = v;
  }
}

// ======================= launch =======================

extern "C" void kernel_launch(void* const* d_in, const int* in_sizes, int n_in,
                              void* d_out, int out_size, void* d_ws, size_t ws_size,
                              hipStream_t stream) {
  const float* x     = (const float*)d_in[0];
  const float* W     = (const float*)d_in[1];
  const float* gamma = (const float*)d_in[2];
  const float* beta  = (const float*)d_in[3];
  const int*   oidx  = (const int*)d_in[4];

  // ws layout (~270 MB; 514 MB proven available in prior rounds)
  const size_t XB_OFF     = 0;             // 128,000,000
  const size_t PART_OFF   = 128000000;     //  71,680,000 (280K x 256B, reused per pass)
  const size_t CNT8_OFF   = 199680000;     //  16,000,000
  const size_t CUR8_OFF   = 215680000;     //  16,000,000
  const size_t OFFS8_OFF  = 231680000;     //  16,000,128 (8 x OS ints)
  const size_t SSRC_OFF   = 247680128;     //   8,000,000
  const size_t SGSL_OFF   = 255680128;     //   8,000,000
  const size_t GCNT_OFF   = 263680128;     //   2,000,000
  const size_t GOFFS_OFF  = 265680128;     //   2,000,016
  const size_t GCUR_OFF   = 267680144;     //   2,000,000
  const size_t WT_OFF     = 269680144;     //     524,288
  const size_t BSUM8_OFF  = 270204432;     //      15,648
  const size_t BSUMX8_OFF = 270220080;     //      15,648
  const size_t GBSUM_OFF  = 270235728;     //       1,968
  const size_t GBSUMX_OFF = 270237696;     //       1,968
  const size_t STATS_OFF  = 270239664;     //       1,024
  const size_t NEED       = 270240688;

  if (ws_size >= NEED) {
    char* ws = (char*)d_ws;
    char* xbb    = ws + XB_OFF;
    char* partials = ws + PART_OFF;
    int* cnt8    = (int*)(ws + CNT8_OFF);
    int* cur8    = (int*)(ws + CUR8_OFF);
    int* offs8   = (int*)(ws + OFFS8_OFF);
    int* ssrc    = (int*)(ws + SSRC_OFF);
    int* sgslot  = (int*)(ws + SGSL_OFF);
    int* gcnt    = (int*)(ws + GCNT_OFF);
    int* goffs   = (int*)(ws + GOFFS_OFF);
    int* gcur    = (int*)(ws + GCUR_OFF);
    __bf16* Wt   = (__bf16*)(ws + WT_OFF);
    int* bsum8   = (int*)(ws + BSUM8_OFF);
    int* bsumx8  = (int*)(ws + BSUMX8_OFF);
    int* gbsum   = (int*)(ws + GBSUM_OFF);
    int* gbsumx  = (int*)(ws + GBSUMX_OFF);
    float* stats = (float*)(ws + STATS_OFF);

    hipMemsetAsync(cnt8, 0, (size_t)KVOL * N_OUT * sizeof(int), stream);
    hipMemsetAsync(gcnt, 0, (size_t)N_OUT * sizeof(int), stream);
    hipMemsetAsync(stats, 0, 256 * sizeof(float), stream);

    xconv_kernel<<<(N_IN * INC / 8 + 255) / 256, 256, 0, stream>>>(x, (uint32_t*)xbb);
    wconv_kernel<<<(KVOL * OUTC * INC + 255) / 256, 256, 0, stream>>>(W, Wt);
    hist8_kernel<<<dim3((N_IN + 255) / 256, KVOL), 256, 0, stream>>>(oidx, cnt8, gcnt);
    // per-k scans -> offs8 + cur8
    scan1s_kernel<<<dim3(DCHUNKS, KVOL), 256, 0, stream>>>(cnt8, offs8, bsum8);
    scan2s_kernel<<<KVOL, 512, 0, stream>>>(bsum8, bsumx8);
    scan3s_kernel<<<dim3((N_OUT + 255) / 256, KVOL), 256, 0, stream>>>(offs8, cur8, bsumx8);
    // global scan -> goffs + gcur
    scan1s_kernel<<<dim3(DCHUNKS, 1), 256, 0, stream>>>(gcnt, goffs, gbsum);
    scan2s_kernel<<<1, 512, 0, stream>>>(gbsum, gbsumx);
    scan3g_kernel<<<(N_OUT + 255) / 256, 256, 0, stream>>>(goffs, gcur, gbsumx);
    fill_kernel<<<dim3((N_IN + 255) / 256, KVOL), 256, 0, stream>>>(
        oidx, cur8, gcur, ssrc, sgslot);

    // L3-tiled passes over destination space
    for (int p = 0; p < NPASS; ++p) {
      int dlo = p * DPASS;
      int dhi = (p + 1 == NPASS) ? N_OUT : (p + 1) * DPASS;
      gemm_gather_store_kernel<<<dim3(512, KVOL), 512, 0, stream>>>(
          xbb, Wt, ssrc, sgslot, offs8, goffs, partials, dlo, dhi);
      reduce_stats_kernel<<<2048, 256, 0, stream>>>(
          partials, goffs, (char*)d_out, stats, dlo, dhi);
    }
    norm_kernel<<<1024, 256, 0, stream>>>((char*)d_out, stats, gamma, beta);
  } else {
    // fallback: proven round-2 atomic pipeline (~526 KB ws)
    __bf16* Wt   = (__bf16*)d_ws;
    float* stats = (float*)((char*)d_ws + (size_t)KVOL * OUTC * INC * 2);
    float* out = (float*)d_out;

    hipMemsetAsync(d_out, 0, (size_t)N_OUT * OUTC * sizeof(float), stream);
    hipMemsetAsync(stats, 0, 256 * sizeof(float), stream);

    wconv_kernel<<<(KVOL * OUTC * INC + 255) / 256, 256, 0, stream>>>(W, Wt);
    gemm_scatter_f32_kernel<<<(N_IN + 63) / 64, 512, 0, stream>>>(x, Wt, oidx, out);
    stats_f32_kernel<<<1024, 256, 0, stream>>>(out, stats);
    norm_f32_kernel<<<2048, 256, 0, stream>>>(out, stats, gamma, beta);
  }
}

// Round 8
// 855.123 us; speedup vs baseline: 3.4101x; 3.0306x over previous
//
#include <hip/hip_runtime.h>
#include <hip/hip_bf16.h>
#include <stdint.h>

#define N_IN 250000
#define N_OUT 500000
#define INC 256
#define OUTC 128
#define KVOL 8
#define NTOT (KVOL * N_IN)   // 2,000,000 contributions
#define BN_EPS 1e-5f

typedef __bf16 bf16x8_t __attribute__((ext_vector_type(8)));
typedef __bf16 bf16x4_t __attribute__((ext_vector_type(4)));
typedef float f32x4_t __attribute__((ext_vector_type(4)));
typedef uint32_t u32x4_t __attribute__((ext_vector_type(4)));

__device__ __forceinline__ __bf16 f2bf(float x) {
  union { float f; uint32_t u; } v; v.f = x;
  uint32_t r = v.u + 0x7FFFu + ((v.u >> 16) & 1u);
  union { uint16_t s; __bf16 b; } o; o.s = (uint16_t)(r >> 16);
  return o.b;
}

__device__ __forceinline__ uint32_t pack2bf(float lo, float hi) {
  union { float f; uint32_t u; } a, b; a.f = lo; b.f = hi;
  uint32_t ra = a.u + 0x7FFFu + ((a.u >> 16) & 1u);
  uint32_t rb = b.u + 0x7FFFu + ((b.u >> 16) & 1u);
  return (ra >> 16) | (rb & 0xFFFF0000u);
}

__device__ __forceinline__ float bflo(uint32_t w) {
  union { uint32_t u; float f; } v; v.u = w << 16; return v.f;
}
__device__ __forceinline__ float bfhi(uint32_t w) {
  union { uint32_t u; float f; } v; v.u = w & 0xFFFF0000u; return v.f;
}

// W[k][inc][outc] fp32 -> Wt[k][outc][inc] bf16 (contiguous MFMA fragments)
__global__ void wconv_kernel(const float* __restrict__ W, __bf16* __restrict__ Wt) {
  int f = blockIdx.x * blockDim.x + threadIdx.x;
  if (f >= KVOL * OUTC * INC) return;
  int i = f & (INC - 1);
  int o = (f >> 8) & (OUTC - 1);
  int k = f >> 15;
  Wt[f] = f2bf(W[(k * INC + i) * OUTC + o]);
}

// ======================= counting-sort passes (global d-order) =======================

__global__ void hist_kernel(const int* __restrict__ oidx, int* __restrict__ cnt) {
  int g = blockIdx.x * 256 + threadIdx.x;
  if (g < NTOT) atomicAdd(&cnt[oidx[g]], 1);
}

// per-1024-chunk exclusive scan + chunk totals
__global__ void scan1_kernel(const int* __restrict__ cnt, int* __restrict__ offs,
                             int* __restrict__ bsum) {
  __shared__ int sd[256];
  int t = threadIdx.x;
  int base = blockIdx.x * 1024 + t * 4;
  int v0 = 0, v1 = 0, v2 = 0, v3 = 0;
  if (base + 3 < N_OUT) {
    int4 v = *(const int4*)&cnt[base];
    v0 = v.x; v1 = v.y; v2 = v.z; v3 = v.w;
  } else {
    if (base     < N_OUT) v0 = cnt[base];
    if (base + 1 < N_OUT) v1 = cnt[base + 1];
    if (base + 2 < N_OUT) v2 = cnt[base + 2];
  }
  int s = v0 + v1 + v2 + v3;
  sd[t] = s; __syncthreads();
  for (int o = 1; o < 256; o <<= 1) {
    int a = (t >= o) ? sd[t - o] : 0;
    __syncthreads();
    sd[t] += a;
    __syncthreads();
  }
  int excl = sd[t] - s;
  if (base     < N_OUT) offs[base]     = excl;
  if (base + 1 < N_OUT) offs[base + 1] = excl + v0;
  if (base + 2 < N_OUT) offs[base + 2] = excl + v0 + v1;
  if (base + 3 < N_OUT) offs[base + 3] = excl + v0 + v1 + v2;
  if (t == 255) bsum[blockIdx.x] = sd[255];
}

// single-block exclusive scan of chunk totals (nb <= 512)
__global__ void scan2_kernel(const int* __restrict__ bsum, int* __restrict__ bsumx, int nb) {
  __shared__ int sd[512];
  int t = threadIdx.x;
  int s = (t < nb) ? bsum[t] : 0;
  sd[t] = s; __syncthreads();
  for (int o = 1; o < 512; o <<= 1) {
    int a = (t >= o) ? sd[t - o] : 0;
    __syncthreads();
    sd[t] += a;
    __syncthreads();
  }
  if (t < nb) bsumx[t] = sd[t] - s;
}

__global__ void scan3_kernel(int* __restrict__ offs, int* __restrict__ cursor,
                             const int* __restrict__ bsumx) {
  int g = blockIdx.x * 256 + threadIdx.x;
  if (g < N_OUT) {
    int v = offs[g] + bsumx[g >> 10];
    offs[g] = v;
    cursor[g] = v;
  }
  if (g == 0) offs[N_OUT] = NTOT;
}

__global__ void fill_kernel(const int* __restrict__ oidx, int* __restrict__ cursor,
                            int* __restrict__ slot) {
  int g = blockIdx.x * 256 + threadIdx.x;
  if (g < NTOT) {
    int d = oidx[g];
    slot[g] = atomicAdd(&cursor[d], 1);
  }
}

// ======================= GEMM -> d-sorted partials (v2: no store barriers) =======================

#define TM 64
#define LDS_STRIDE 264  // bf16 elems per xs row (256 + 8 pad)

// 512 threads = 8 waves; wave w handles kernel offset k=w. Computes the
// transposed product D[chan][voxel] for a 64-row x tile; per-wave LDS staging
// (wave-synchronous, NO block barriers in the store loop) then 256B bf16
// partial rows stored to slot[k*N_IN+i] positions.
__global__ __launch_bounds__(512, 1) void gemm_store_kernel(
    const float* __restrict__ x, const __bf16* __restrict__ Wt,
    const int* __restrict__ slot, char* __restrict__ partials) {
  __shared__ __bf16 xs[TM * LDS_STRIDE];              // 33792 B
  __shared__ __align__(16) uint2 stg[8][16][34];      // 34816 B, 272B row stride
  const int t = threadIdx.x;
  const int row0 = blockIdx.x * TM;

  // ---- stage x tile (64 x 256 fp32 -> bf16 LDS), nt loads, zero-fill OOB ----
  #pragma unroll
  for (int i = 0; i < 8; ++i) {
    int f = t + i * 512;
    int r = f >> 6;
    int c4 = f & 63;
    int grow = row0 + r;
    f32x4_t v = {0.f, 0.f, 0.f, 0.f};
    if (grow < N_IN)
      v = __builtin_nontemporal_load((const f32x4_t*)x + (size_t)grow * 64 + c4);
    bf16x4_t bv;
    bv[0] = f2bf(v[0]); bv[1] = f2bf(v[1]); bv[2] = f2bf(v[2]); bv[3] = f2bf(v[3]);
    *(bf16x4_t*)&xs[r * LDS_STRIDE + c4 * 4] = bv;
  }
  __syncthreads();

  const int w  = t >> 6;
  const int l  = t & 63;
  const int lr = l & 15;
  const int lg = l >> 4;

  f32x4_t accT[8][4];
  #pragma unroll
  for (int n = 0; n < 8; ++n)
    #pragma unroll
    for (int m = 0; m < 4; ++m)
      accT[n][m] = (f32x4_t){0.f, 0.f, 0.f, 0.f};

  const __bf16* Wk = Wt + (size_t)w * OUTC * INC;

  #pragma unroll
  for (int s = 0; s < 8; ++s) {
    bf16x8_t a[4], b[8];
    #pragma unroll
    for (int m = 0; m < 4; ++m)
      a[m] = *(const bf16x8_t*)&xs[(m * 16 + lr) * LDS_STRIDE + s * 32 + lg * 8];
    #pragma unroll
    for (int n = 0; n < 8; ++n)
      b[n] = *(const bf16x8_t*)&Wk[(n * 16 + lr) * INC + s * 32 + lg * 8];
    // swapped operands -> D[chan][voxel]
    #pragma unroll
    for (int n = 0; n < 8; ++n)
      #pragma unroll
      for (int m = 0; m < 4; ++m)
        accT[n][m] = __builtin_amdgcn_mfma_f32_16x16x32_bf16(b[n], a[m], accT[n][m], 0, 0, 0);
  }

  // ---- per-wave staged store: wave-synchronous, no block barriers ----
  // lane (lg,lr) holds voxel m*16+lr, chans n*16+lg*4+{0..3}
  const int r2 = l >> 2;         // row within the 16-row subtile
  const int p  = l & 3;          // 64B quarter of the 256B row
  const int sbase = w * N_IN + row0;
  #pragma unroll
  for (int m = 0; m < 4; ++m) {
    #pragma unroll
    for (int n = 0; n < 8; ++n) {
      uint2 pk;
      pk.x = pack2bf(accT[n][m][0], accT[n][m][1]);
      pk.y = pack2bf(accT[n][m][2], accT[n][m][3]);
      stg[w][lr][n * 4 + lg] = pk;
    }
    // wave-internal LDS write->read ordering (per-wave buffer, lockstep wave)
    asm volatile("s_waitcnt lgkmcnt(0)" ::: "memory");
    __builtin_amdgcn_wave_barrier();
    int grow = row0 + m * 16 + r2;
    if (grow < N_IN) {
      int gs = slot[sbase + m * 16 + r2];     // 4 lanes same addr -> broadcast
      const u32x4_t* rp = (const u32x4_t*)&stg[w][r2][0];
      char* dst = partials + (size_t)gs * 256 + p * 64;
      #pragma unroll
      for (int q = 0; q < 4; ++q)
        *(u32x4_t*)(dst + q * 16) = rp[p * 4 + q];
    }
    __builtin_amdgcn_wave_barrier();
  }
}

// ============== segmented reduce + fused BN stats ==============

// 256 thr = 16 groups x 16 lanes; group handles one output row at a time:
// sums its contiguous partials (nt loads: read-once), writes bf16 accum into
// d_out slot, and accumulates per-channel sum/sumsq over the rounded values.
__global__ __launch_bounds__(256) void reduce_stats_kernel(
    const char* __restrict__ partials, const int* __restrict__ offs,
    char* __restrict__ accb, float* __restrict__ stats) {
  const int t = threadIdx.x;
  const int lane16 = t & 15;
  const int grp = t >> 4;
  float s[8], q[8];
  #pragma unroll
  for (int i = 0; i < 8; ++i) { s[i] = 0.f; q[i] = 0.f; }

  for (int d = blockIdx.x * 16 + grp; d < N_OUT; d += gridDim.x * 16) {
    int j0 = offs[d], j1 = offs[d + 1];
    float a[8];
    #pragma unroll
    for (int i = 0; i < 8; ++i) a[i] = 0.f;
    for (int j = j0; j < j1; ++j) {
      u32x4_t v = __builtin_nontemporal_load(
          (const u32x4_t*)(partials + (size_t)j * 256 + lane16 * 16));
      a[0] += bflo(v[0]); a[1] += bfhi(v[0]);
      a[2] += bflo(v[1]); a[3] += bfhi(v[1]);
      a[4] += bflo(v[2]); a[5] += bfhi(v[2]);
      a[6] += bflo(v[3]); a[7] += bfhi(v[3]);
    }
    u32x4_t o;
    o[0] = pack2bf(a[0], a[1]); o[1] = pack2bf(a[2], a[3]);
    o[2] = pack2bf(a[4], a[5]); o[3] = pack2bf(a[6], a[7]);
    *(u32x4_t*)(accb + (size_t)d * 512 + lane16 * 16) = o;
    #pragma unroll
    for (int u = 0; u < 4; ++u) {
      float f0 = bflo(o[u]), f1 = bfhi(o[u]);
      s[2 * u] += f0;     q[2 * u] += f0 * f0;
      s[2 * u + 1] += f1; q[2 * u + 1] += f1 * f1;
    }
  }

  __shared__ float reds[16][16][8];
  __shared__ float redq[16][16][8];
  #pragma unroll
  for (int i = 0; i < 8; ++i) { reds[grp][lane16][i] = s[i]; redq[grp][lane16][i] = q[i]; }
  __syncthreads();
  if (t < 128) {
    float acc = 0.f;
    #pragma unroll
    for (int g2 = 0; g2 < 16; ++g2) acc += reds[g2][t >> 3][t & 7];
    atomicAdd(&stats[t], acc);
  } else {
    int c = t - 128;
    float acc = 0.f;
    #pragma unroll
    for (int g2 = 0; g2 < 16; ++g2) acc += redq[g2][c >> 3][c & 7];
    atomicAdd(&stats[128 + c], acc);
  }
}

// Read bf16 accum from row slot, write normalized fp32 over the full slot (nt).
__global__ void norm_kernel(char* __restrict__ outb, const float* __restrict__ stats,
                            const float* __restrict__ gamma, const float* __restrict__ beta) {
  const int t = threadIdx.x;
  const int j = t & 15;
  const int ro = t >> 4;
  const float inv_n = 1.0f / (float)N_OUT;
  float sc[8], sh[8];
  #pragma unroll
  for (int i = 0; i < 8; ++i) {
    int c = j * 8 + i;
    float mean = stats[c] * inv_n;
    float var  = stats[128 + c] * inv_n - mean * mean;
    float s = gamma[c] * rsqrtf(var + BN_EPS);
    sc[i] = s;
    sh[i] = beta[c] - mean * s;
  }
  for (int r = blockIdx.x * 16 + ro; r < N_OUT; r += gridDim.x * 16) {
    u32x4_t v = *(const u32x4_t*)(outb + (size_t)r * 512 + j * 16);
    f32x4_t o0, o1;
    #pragma unroll
    for (int u = 0; u < 4; ++u) {
      float f0 = bflo(v[u]) * sc[2 * u] + sh[2 * u];
      float f1 = bfhi(v[u]) * sc[2 * u + 1] + sh[2 * u + 1];
      if (u < 2) { o0[2 * u] = f0; o0[2 * u + 1] = f1; }
      else       { o1[2 * (u - 2)] = f0; o1[2 * (u - 2) + 1] = f1; }
    }
    __builtin_nontemporal_store(o0, (f32x4_t*)(outb + (size_t)r * 512 + j * 32));
    __builtin_nontemporal_store(o1, (f32x4_t*)(outb + (size_t)r * 512 + j * 32 + 16));
  }
}

// ======================= fallback (round-2 proven atomic path) =======================

__global__ __launch_bounds__(512, 1) void gemm_scatter_f32_kernel(
    const float* __restrict__ x, const __bf16* __restrict__ Wt,
    const int* __restrict__ out_idx, float* __restrict__ acc) {
  __shared__ __bf16 xs[TM * LDS_STRIDE];
  const int t = threadIdx.x;
  const int row0 = blockIdx.x * TM;
  #pragma unroll
  for (int i = 0; i < 8; ++i) {
    int f = t + i * 512;
    int r = f >> 6;
    int c4 = f & 63;
    int grow = row0 + r;
    float4 v = make_float4(0.f, 0.f, 0.f, 0.f);
    if (grow < N_IN) v = ((const float4*)x)[(size_t)grow * 64 + c4];
    bf16x4_t bv;
    bv[0] = f2bf(v.x); bv[1] = f2bf(v.y); bv[2] = f2bf(v.z); bv[3] = f2bf(v.w);
    *(bf16x4_t*)&xs[r * LDS_STRIDE + c4 * 4] = bv;
  }
  __syncthreads();
  const int w = t >> 6, l = t & 63, lr = l & 15, lg = l >> 4;
  f32x4_t accr[4][8];
  #pragma unroll
  for (int m = 0; m < 4; ++m)
    #pragma unroll
    for (int n = 0; n < 8; ++n)
      accr[m][n] = (f32x4_t){0.f, 0.f, 0.f, 0.f};
  const __bf16* Wkp = Wt + (size_t)w * OUTC * INC;
  #pragma unroll
  for (int s = 0; s < 8; ++s) {
    bf16x8_t a[4], b[8];
    #pragma unroll
    for (int m = 0; m < 4; ++m)
      a[m] = *(const bf16x8_t*)&xs[(m * 16 + lr) * LDS_STRIDE + s * 32 + lg * 8];
    #pragma unroll
    for (int n = 0; n < 8; ++n)
      b[n] = *(const bf16x8_t*)&Wkp[(n * 16 + lr) * INC + s * 32 + lg * 8];
    #pragma unroll
    for (int m = 0; m < 4; ++m)
      #pragma unroll
      for (int n = 0; n < 8; ++n)
        accr[m][n] = __builtin_amdgcn_mfma_f32_16x16x32_bf16(a[m], b[n], accr[m][n], 0, 0, 0);
  }
  const int* oidx = out_idx + (size_t)w * N_IN;
  #pragma unroll
  for (int m = 0; m < 4; ++m) {
    int rbase = m * 16 + lg * 4;
    #pragma unroll
    for (int reg = 0; reg < 4; ++reg) {
      int grow = row0 + rbase + reg;
      if (grow < N_IN) {
        int dst = oidx[grow];
        float* ap = acc + (size_t)dst * OUTC;
        #pragma unroll
        for (int n = 0; n < 8; ++n)
          atomicAdd(&ap[n * 16 + lr], accr[m][n][reg]);
      }
    }
  }
}

__global__ void stats_f32_kernel(const float* __restrict__ acc, float* __restrict__ stats) {
  const int t = threadIdx.x;
  const int c4 = t & 31;
  const int ro = t >> 5;
  f32x4_t s = {0.f, 0.f, 0.f, 0.f}, q = {0.f, 0.f, 0.f, 0.f};
  for (int r = blockIdx.x * 8 + ro; r < N_OUT; r += gridDim.x * 8) {
    f32x4_t v = ((const f32x4_t*)acc)[(size_t)r * 32 + c4];
    s += v; q += v * v;
  }
  __shared__ float redl[256][8];
  #pragma unroll
  for (int j = 0; j < 4; ++j) { redl[t][j] = s[j]; redl[t][4 + j] = q[j]; }
  __syncthreads();
  if (t < 32) {
    float S[4] = {0.f, 0.f, 0.f, 0.f}, Q[4] = {0.f, 0.f, 0.f, 0.f};
    for (int r2 = 0; r2 < 8; ++r2)
      #pragma unroll
      for (int j = 0; j < 4; ++j) {
        S[j] += redl[r2 * 32 + t][j];
        Q[j] += redl[r2 * 32 + t][4 + j];
      }
    #pragma unroll
    for (int j = 0; j < 4; ++j) {
      atomicAdd(&stats[t * 4 + j], S[j]);
      atomicAdd(&stats[128 + t * 4 + j], Q[j]);
    }
  }
}

__global__ void norm_f32_kernel(float* __restrict__ out, const float* __restrict__ stats,
                                const float* __restrict__ gamma, const float* __restrict__ beta) {
  const int t = threadIdx.x;
  const int c4 = t & 31;
  const int ro = t >> 5;
  const float inv_n = 1.0f / (float)N_OUT;
  float sc[4], sh[4];
  #pragma unroll
  for (int j = 0; j < 4; ++j) {
    int c = c4 * 4 + j;
    float mean = stats[c] * inv_n;
    float var  = stats[128 + c] * inv_n - mean * mean;
    float s = gamma[c] * rsqrtf(var + BN_EPS);
    sc[j] = s;
    sh[j] = beta[c] - mean * s;
  }
  for (int r = blockIdx.x * 8 + ro; r < N_OUT; r += gridDim.x * 8) {
    f32x4_t v = ((const f32x4_t*)out)[(size_t)r * 32 + c4];
    #pragma unroll
    for (int j = 0; j < 4; ++j) v[j] = v[j] * sc[j] + sh[j];
    ((f32x4_t*)out)[(size_t)r * 32 + c4] = v;
  }
}

// ======================= launch =======================

extern "C" void kernel_launch(void* const* d_in, const int* in_sizes, int n_in,
                              void* d_out, int out_size, void* d_ws, size_t ws_size,
                              hipStream_t stream) {
  const float* x     = (const float*)d_in[0];
  const float* W     = (const float*)d_in[1];
  const float* gamma = (const float*)d_in[2];
  const float* beta  = (const float*)d_in[3];
  const int*   oidx  = (const int*)d_in[4];

  // ws layout (identical to round-4 proven path C)
  const size_t P_OFF     = 0;                       // partials: 512,000,000
  const size_t SLOT_OFF  = 512000000;               // 8,000,000
  const size_t CNT_OFF   = 520000000;               // 2,000,000
  const size_t OFFS_OFF  = 522000000;               // 2,000,384
  const size_t CURS_OFF  = 524000384;               // 2,000,000
  const size_t BSUM_OFF  = 526000384;               // 4,096
  const size_t BSUMX_OFF = 526004480;               // 4,096
  const size_t WT_OFF    = 526008576;               // 524,288
  const size_t STATS_OFF = 526532864;               // 1,024
  const size_t NEED      = 526533888;

  if (ws_size >= NEED) {
    char* ws = (char*)d_ws;
    char* partials = ws + P_OFF;
    int* slot   = (int*)(ws + SLOT_OFF);
    int* cnt    = (int*)(ws + CNT_OFF);
    int* offs   = (int*)(ws + OFFS_OFF);
    int* cursor = (int*)(ws + CURS_OFF);
    int* bsum   = (int*)(ws + BSUM_OFF);
    int* bsumx  = (int*)(ws + BSUMX_OFF);
    __bf16* Wt  = (__bf16*)(ws + WT_OFF);
    float* stats = (float*)(ws + STATS_OFF);

    hipMemsetAsync(cnt, 0, N_OUT * sizeof(int), stream);
    hipMemsetAsync(stats, 0, 256 * sizeof(float), stream);

    wconv_kernel<<<(KVOL * OUTC * INC + 255) / 256, 256, 0, stream>>>(W, Wt);
    hist_kernel<<<(NTOT + 255) / 256, 256, 0, stream>>>(oidx, cnt);
    const int NB1 = (N_OUT + 1023) / 1024;  // 489
    scan1_kernel<<<NB1, 256, 0, stream>>>(cnt, offs, bsum);
    scan2_kernel<<<1, 512, 0, stream>>>(bsum, bsumx, NB1);
    scan3_kernel<<<(N_OUT + 255) / 256, 256, 0, stream>>>(offs, cursor, bsumx);
    fill_kernel<<<(NTOT + 255) / 256, 256, 0, stream>>>(oidx, cursor, slot);
    gemm_store_kernel<<<(N_IN + TM - 1) / TM, 512, 0, stream>>>(x, Wt, slot, partials);
    reduce_stats_kernel<<<2048, 256, 0, stream>>>(partials, offs, (char*)d_out, stats);
    norm_kernel<<<512, 256, 0, stream>>>((char*)d_out, stats, gamma, beta);
  } else {
    // fallback: proven round-2 atomic pipeline (needs only ~526 KB ws)
    __bf16* Wt   = (__bf16*)d_ws;
    float* stats = (float*)((char*)d_ws + (size_t)KVOL * OUTC * INC * 2);
    float* out = (float*)d_out;

    hipMemsetAsync(d_out, 0, (size_t)N_OUT * OUTC * sizeof(float), stream);
    hipMemsetAsync(stats, 0, 256 * sizeof(float), stream);

    wconv_kernel<<<(KVOL * OUTC * INC + 255) / 256, 256, 0, stream>>>(W, Wt);
    gemm_scatter_f32_kernel<<<(N_IN + TM - 1) / TM, 512, 0, stream>>>(x, Wt, oidx, out);
    stats_f32_kernel<<<1024, 256, 0, stream>>>(out, stats);
    norm_f32_kernel<<<2048, 256, 0, stream>>>(out, stats, gamma, beta);
  }
}